// Round 4
// baseline (122.814 us; speedup 1.0000x reference)
//
#include <hip/hip_runtime.h>
#include <hip/hip_bf16.h>

// MeanAggregator: out[n, :] = mean_{s<12} feature[idx[n,s], :]
// feature: [200000, 64] f32, idx: [100000, 12] int32, out: [100000, 64] f32
//
// 16 lanes per node, each lane owns one float4 (16B) of the 256B row.
// R4 change: force true MLP. R2/R3 VGPR counts (28/36) prove the compiler
// serialized the gathers (acc += load chains + occupancy-targeted regalloc).
// Now: 12 loads into independent locals -> tree sum, and
// __launch_bounds__(256, 1) to relax the VGPR budget so all 12
// global_load_dwordx4 issue back-to-back before the first s_waitcnt.

#define N_NODES  100000
#define N_SAMPLE 12
#define D_FEAT   64
#define LANES_PER_NODE 16   // D_FEAT/4 floats per float4

typedef float  fvec4 __attribute__((ext_vector_type(4)));
typedef int    ivec4 __attribute__((ext_vector_type(4)));

__global__ __launch_bounds__(256, 1) void mean_agg_kernel(
    const fvec4* __restrict__ feat4,   // [N_TOTAL, 16] as fvec4
    const int*   __restrict__ idx,     // [N_NODES, N_SAMPLE]
    fvec4*       __restrict__ out4)    // [N_NODES, 16] as fvec4
{
    const int t    = blockIdx.x * blockDim.x + threadIdx.x;
    const int node = t >> 4;          // /16
    const int c    = t & 15;          // float4 slot within the row
    if (node >= N_NODES) return;

    // 12 indices = 3 x int4, broadcast across the 16 lanes of this node.
    const ivec4* nidx = (const ivec4*)(idx + node * N_SAMPLE);
    const ivec4 j0 = nidx[0];
    const ivec4 j1 = nidx[1];
    const ivec4 j2 = nidx[2];

    // 12 independent destination registers -> 12 loads in flight.
    const fvec4 v0  = feat4[(size_t)j0.x * LANES_PER_NODE + c];
    const fvec4 v1  = feat4[(size_t)j0.y * LANES_PER_NODE + c];
    const fvec4 v2  = feat4[(size_t)j0.z * LANES_PER_NODE + c];
    const fvec4 v3  = feat4[(size_t)j0.w * LANES_PER_NODE + c];
    const fvec4 v4  = feat4[(size_t)j1.x * LANES_PER_NODE + c];
    const fvec4 v5  = feat4[(size_t)j1.y * LANES_PER_NODE + c];
    const fvec4 v6  = feat4[(size_t)j1.z * LANES_PER_NODE + c];
    const fvec4 v7  = feat4[(size_t)j1.w * LANES_PER_NODE + c];
    const fvec4 v8  = feat4[(size_t)j2.x * LANES_PER_NODE + c];
    const fvec4 v9  = feat4[(size_t)j2.y * LANES_PER_NODE + c];
    const fvec4 v10 = feat4[(size_t)j2.z * LANES_PER_NODE + c];
    const fvec4 v11 = feat4[(size_t)j2.w * LANES_PER_NODE + c];

    // Tree sum (reassociation is fine: threshold is ~0.033, fp32 sum of 12).
    const fvec4 s01 = v0 + v1,   s23  = v2 + v3;
    const fvec4 s45 = v4 + v5,   s67  = v6 + v7;
    const fvec4 s89 = v8 + v9,   sAB  = v10 + v11;
    const fvec4 a   = s01 + s23, b    = s45 + s67, d = s89 + sAB;
    fvec4 acc = (a + b) + d;

    acc *= (1.0f / (float)N_SAMPLE);

    __builtin_nontemporal_store(acc, out4 + t);
}

extern "C" void kernel_launch(void* const* d_in, const int* in_sizes, int n_in,
                              void* d_out, int out_size, void* d_ws, size_t ws_size,
                              hipStream_t stream) {
    const fvec4* feat4 = (const fvec4*)d_in[0];
    const int*   idx   = (const int*)d_in[1];
    fvec4*       out4  = (fvec4*)d_out;

    const int total_threads = N_NODES * LANES_PER_NODE;   // 1.6M
    const int block = 256;
    const int grid  = (total_threads + block - 1) / block; // 6250

    mean_agg_kernel<<<grid, block, 0, stream>>>(feat4, idx, out4);
}